// Round 1
// baseline (394.553 us; speedup 1.0000x reference)
//
#include <hip/hip_runtime.h>
#include <hip/hip_bf16.h>

// ---------- types ----------
typedef short bf16x8 __attribute__((ext_vector_type(8)));      // 8 bf16 in 4 VGPRs
typedef unsigned short u16x8 __attribute__((ext_vector_type(8)));
typedef float f32x4 __attribute__((ext_vector_type(4)));
using bf16 = __hip_bfloat16;

#define EMB 768
#define NHEAD 12
#define BATCH 8
#define NTOK 4096
#define BNTOK 32768   // BATCH*NTOK

__device__ __forceinline__ float b2f(unsigned short u) {
    union { unsigned int i; float f; } x; x.i = ((unsigned int)u) << 16; return x.f;
}
__device__ __forceinline__ unsigned short f2bu(float f) {
    bf16 h = __float2bfloat16(f);
    return *reinterpret_cast<unsigned short*>(&h);
}

__device__ __forceinline__ void gload_lds16(const void* g, void* l) {
    __builtin_amdgcn_global_load_lds(
        (const __attribute__((address_space(1))) unsigned int*)g,
        (__attribute__((address_space(3))) unsigned int*)l,
        16, 0, 0);
}

// ---------- cast x (fp32 -> bf16), vectorized ----------
__global__ __launch_bounds__(256) void cast_x_kernel(const float* __restrict__ x,
                                                     bf16* __restrict__ xb, int n8) {
    int i = blockIdx.x * blockDim.x + threadIdx.x;
    if (i >= n8) return;
    const float4* xv = (const float4*)x;
    float4 a = xv[i * 2], b = xv[i * 2 + 1];
    u16x8 o;
    o[0] = f2bu(a.x); o[1] = f2bu(a.y); o[2] = f2bu(a.z); o[3] = f2bu(a.w);
    o[4] = f2bu(b.x); o[5] = f2bu(b.y); o[6] = f2bu(b.z); o[7] = f2bu(b.w);
    ((u16x8*)xb)[i] = o;
}

// ---------- weight prep: W^T casts + stacked bias ----------
__global__ __launch_bounds__(256) void prep_w_kernel(
    const float* __restrict__ Wq, const float* __restrict__ Wk,
    const float* __restrict__ Wv, const float* __restrict__ Wo,
    const float* __restrict__ bq, const float* __restrict__ bk, const float* __restrict__ bv,
    bf16* __restrict__ WqkvT, bf16* __restrict__ WoT, float* __restrict__ bqkv) {
    const int NQKV = 2304 * 768, NO = 768 * 768;
    int i = blockIdx.x * blockDim.x + threadIdx.x;
    if (i < NQKV) {
        int nrow = i / 768, k = i % 768;
        const float* W = (nrow < 768) ? Wq : (nrow < 1536 ? Wk : Wv);
        int c = nrow % 768;
        WqkvT[i] = __float2bfloat16(W[k * 768 + c]);
    } else if (i < NQKV + NO) {
        int j = i - NQKV; int nrow = j / 768, k = j % 768;
        WoT[j] = __float2bfloat16(Wo[k * 768 + nrow]);
    } else if (i < NQKV + NO + 2304) {
        int j = i - NQKV - NO;
        bqkv[j] = (j < 768) ? bq[j] : (j < 1536 ? bk[j - 768] : bv[j - 1536]);
    }
}

// ---------- 128x128 bf16 GEMM (m97 structure), B^T input ----------
// MODE 0: C split to Q/K/V bf16 buffers (+bias). MODE 1: C fp32 to Cout (+bo).
template <int MODE>
__global__ __launch_bounds__(256) void gemm_bt(
    const bf16* __restrict__ A, const bf16* __restrict__ BT,
    int M, int N, int K,
    bf16* __restrict__ Q, bf16* __restrict__ Kb, bf16* __restrict__ V,
    const float* __restrict__ bias,
    float* __restrict__ Cout, const float* __restrict__ bo) {
    __shared__ bf16 As[128 * 32];
    __shared__ bf16 Bs[128 * 32];
    const int tid = threadIdx.x;
    const int lane = tid & 63, wid = tid >> 6;
    const int wm = wid >> 1, wn = wid & 1;
    const int m0 = blockIdx.y * 128, n0 = blockIdx.x * 128;

    f32x4 acc[4][4] = {};
    const int nk = K >> 5;
    const int r0 = tid >> 2, k8 = (tid & 3) << 3;  // staging: chunk tid -> row r0, col k8
    const int lrow = lane & 15, lk = lane >> 4;

    for (int kt = 0; kt < nk; ++kt) {
        const bf16* ga0 = A + (size_t)(m0 + r0) * K + kt * 32 + k8;
        const bf16* gb0 = BT + (size_t)(n0 + r0) * K + kt * 32 + k8;
        char* la0 = (char*)As + (wid * 64) * 16;
        char* la1 = (char*)As + (256 + wid * 64) * 16;
        char* lb0 = (char*)Bs + (wid * 64) * 16;
        char* lb1 = (char*)Bs + (256 + wid * 64) * 16;
        gload_lds16(ga0, la0);
        gload_lds16(ga0 + (size_t)64 * K, la1);
        gload_lds16(gb0, lb0);
        gload_lds16(gb0 + (size_t)64 * K, lb1);
        __syncthreads();
        const bf16x8* Av = (const bf16x8*)As;
        const bf16x8* Bv = (const bf16x8*)Bs;
        bf16x8 a[4], b[4];
#pragma unroll
        for (int i = 0; i < 4; ++i) a[i] = Av[(wm * 64 + i * 16 + lrow) * 4 + lk];
#pragma unroll
        for (int i = 0; i < 4; ++i) b[i] = Bv[(wn * 64 + i * 16 + lrow) * 4 + lk];
#pragma unroll
        for (int mi = 0; mi < 4; ++mi)
#pragma unroll
            for (int ni = 0; ni < 4; ++ni)
                acc[mi][ni] = __builtin_amdgcn_mfma_f32_16x16x32_bf16(a[mi], b[ni], acc[mi][ni], 0, 0, 0);
        __syncthreads();
    }

    const int lq = lane >> 4;
    if (MODE == 0) {
        const int which = n0 / 768;   // 128-tile lies entirely in one of Q/K/V
        bf16* O = (which == 0) ? Q : (which == 1 ? Kb : V);
#pragma unroll
        for (int mi = 0; mi < 4; ++mi)
#pragma unroll
            for (int ni = 0; ni < 4; ++ni) {
                int gcol = n0 + wn * 64 + ni * 16 + lrow;
                int col = gcol - which * 768;
                float bia = bias[gcol];
                size_t rbase = (size_t)(m0 + wm * 64 + mi * 16 + lq * 4);
#pragma unroll
                for (int r = 0; r < 4; ++r)
                    O[(rbase + r) * 768 + col] = __float2bfloat16(acc[mi][ni][r] + bia);
            }
    } else {
#pragma unroll
        for (int mi = 0; mi < 4; ++mi)
#pragma unroll
            for (int ni = 0; ni < 4; ++ni) {
                int col = n0 + wn * 64 + ni * 16 + lrow;
                float bia = bo[col];
                size_t rbase = (size_t)(m0 + wm * 64 + mi * 16 + lq * 4);
#pragma unroll
                for (int r = 0; r < 4; ++r)
                    Cout[(rbase + r) * 768 + col] = acc[mi][ni][r] + bia;
            }
    }
}

// ---------- per-(b,channel) sum of squares over tokens ----------
__global__ __launch_bounds__(256) void sumsq_kernel(
    const bf16* __restrict__ Qb, const bf16* __restrict__ Kb,
    float* __restrict__ ssq, float* __restrict__ ssk) {
    int rc = blockIdx.x, ct = blockIdx.y, b = blockIdx.z;
    int col = ct * 256 + threadIdx.x;
    size_t base = ((size_t)b * NTOK + rc * 256) * 768 + col;
    float sq = 0.f, sk = 0.f;
    for (int i = 0; i < 256; ++i) {
        float q = b2f(*(const unsigned short*)&Qb[base + (size_t)i * 768]);
        float k = b2f(*(const unsigned short*)&Kb[base + (size_t)i * 768]);
        sq += q * q; sk += k * k;
    }
    atomicAdd(&ssq[b * 768 + col], sq);
    atomicAdd(&ssk[b * 768 + col], sk);
}

// ---------- Gram: G[bh][e][j] = sum_n Q[n][e] K[n][j]  (VALU, token-split + atomics) ----------
__global__ __launch_bounds__(256) void gram_kernel(
    const bf16* __restrict__ Qb, const bf16* __restrict__ Kb, float* __restrict__ G) {
    int bh = blockIdx.x >> 2, ch = blockIdx.x & 3;
    int b = bh / NHEAD, h = bh % NHEAD;
    const int t0 = ch * 1024;
    __shared__ float Qs[32][64];
    __shared__ float Ks[32][64];
    int tid = threadIdx.x;
    int e0 = (tid >> 4) << 2, j0 = (tid & 15) << 2;
    float acc[4][4] = {};
    const size_t base = ((size_t)b * NTOK) * 768 + h * 64;
    int lt = tid >> 3, lc = (tid & 7) << 3;
    for (int it = 0; it < 32; ++it) {
        int tok = t0 + it * 32;
        u16x8 qv = *(const u16x8*)(Qb + base + (size_t)(tok + lt) * 768 + lc);
        u16x8 kv = *(const u16x8*)(Kb + base + (size_t)(tok + lt) * 768 + lc);
        __syncthreads();
#pragma unroll
        for (int j = 0; j < 8; ++j) { Qs[lt][lc + j] = b2f(qv[j]); Ks[lt][lc + j] = b2f(kv[j]); }
        __syncthreads();
#pragma unroll
        for (int t = 0; t < 32; ++t) {
            float4 q4 = *(const float4*)&Qs[t][e0];
            float4 k4 = *(const float4*)&Ks[t][j0];
            float q[4] = {q4.x, q4.y, q4.z, q4.w};
            float k[4] = {k4.x, k4.y, k4.z, k4.w};
#pragma unroll
            for (int ii = 0; ii < 4; ++ii)
#pragma unroll
                for (int jj = 0; jj < 4; ++jj) acc[ii][jj] = fmaf(q[ii], k[jj], acc[ii][jj]);
        }
    }
#pragma unroll
    for (int ii = 0; ii < 4; ++ii)
#pragma unroll
        for (int jj = 0; jj < 4; ++jj)
            atomicAdd(&G[(size_t)bh * 4096 + (e0 + ii) * 64 + (j0 + jj)], acc[ii][jj]);
}

// ---------- normalize + softmax + /sqrt(E); store attn^T bf16 ----------
__global__ __launch_bounds__(64) void softmax_kernel(
    const float* __restrict__ G, const float* __restrict__ ssq, const float* __restrict__ ssk,
    bf16* __restrict__ attnT) {
    int bh = blockIdx.x; int b = bh / NHEAD, h = bh % NHEAD;
    int e = threadIdx.x;
    const float* g = G + (size_t)bh * 4096 + e * 64;
    float nq = fmaxf(sqrtf(ssq[b * 768 + h * 64 + e]), 1e-12f);
    float row[64];
    float mx = -1e30f;
#pragma unroll
    for (int j = 0; j < 64; ++j) {
        float nk = fmaxf(sqrtf(ssk[b * 768 + h * 64 + j]), 1e-12f);
        float en = g[j] / (nq * nk);
        row[j] = en;
        mx = fmaxf(mx, en);
    }
    float s = 0.f;
#pragma unroll
    for (int j = 0; j < 64; ++j) { row[j] = __expf(row[j] - mx); s += row[j]; }
    float inv = 0.036084391824351615f / s;   // (1/sqrt(768)) / sum
#pragma unroll
    for (int j = 0; j < 64; ++j)
        attnT[(size_t)bh * 4096 + j * 64 + e] = __float2bfloat16(row[j] * inv);
}

// ---------- PV: Y[b,n,h,:] = V[b,n,h,:] @ attn  (MFMA, K=64) ----------
__global__ __launch_bounds__(256) void pv_kernel(
    const bf16* __restrict__ V, const bf16* __restrict__ attnT, bf16* __restrict__ Y) {
    int tch = blockIdx.x;           // 16 chunks of 256 tokens
    int h = blockIdx.y, b = blockIdx.z;
    int bh = b * NHEAD + h;
    __shared__ bf16 Ats[64 * 64];
    int tid = threadIdx.x, lane = tid & 63, wid = tid >> 6;
    {
        const u16x8* src = (const u16x8*)(attnT + (size_t)bh * 4096);
        u16x8* dst = (u16x8*)Ats;
        dst[tid] = src[tid];
        dst[tid + 256] = src[tid + 256];
    }
    __syncthreads();
    f32x4 acc[4][4] = {};
    const int lrow = lane & 15, lk = lane >> 4;
    const int trow0 = tch * 256 + wid * 64;
#pragma unroll
    for (int ks = 0; ks < 2; ++ks) {
        bf16x8 a[4], bfr[4];
#pragma unroll
        for (int mi = 0; mi < 4; ++mi)
            a[mi] = *(const bf16x8*)(V + (size_t)(b * NTOK + trow0 + mi * 16 + lrow) * 768 +
                                     h * 64 + ks * 32 + lk * 8);
        const bf16x8* Bv = (const bf16x8*)Ats;
#pragma unroll
        for (int ni = 0; ni < 4; ++ni) bfr[ni] = Bv[(ni * 16 + lrow) * 8 + ks * 4 + lk];
#pragma unroll
        for (int mi = 0; mi < 4; ++mi)
#pragma unroll
            for (int ni = 0; ni < 4; ++ni)
                acc[mi][ni] = __builtin_amdgcn_mfma_f32_16x16x32_bf16(a[mi], bfr[ni], acc[mi][ni], 0, 0, 0);
    }
    const int lq = lane >> 4;
#pragma unroll
    for (int mi = 0; mi < 4; ++mi)
#pragma unroll
        for (int ni = 0; ni < 4; ++ni) {
            int col = ni * 16 + lrow;
#pragma unroll
            for (int r = 0; r < 4; ++r) {
                int row = trow0 + mi * 16 + lq * 4 + r;
                Y[(size_t)(b * NTOK + row) * 768 + h * 64 + col] = __float2bfloat16(acc[mi][ni][r]);
            }
        }
}

// ---------- launch ----------
extern "C" void kernel_launch(void* const* d_in, const int* in_sizes, int n_in,
                              void* d_out, int out_size, void* d_ws, size_t ws_size,
                              hipStream_t stream) {
    const float* x  = (const float*)d_in[0];
    const float* Wq = (const float*)d_in[1];
    const float* bq = (const float*)d_in[2];
    const float* Wk = (const float*)d_in[3];
    const float* bk = (const float*)d_in[4];
    const float* Wv = (const float*)d_in[5];
    const float* bv = (const float*)d_in[6];
    const float* Wo = (const float*)d_in[7];
    const float* bo = (const float*)d_in[8];
    float* out = (float*)d_out;

    char* ws = (char*)d_ws;
    bf16*  xb    = (bf16*)(ws + 0);               // 50331648 B ; reused as Y later
    bf16*  WqkvT = (bf16*)(ws + 50331648);        // 3538944
    bf16*  WoT   = (bf16*)(ws + 53870592);        // 1179648
    float* bqkv  = (float*)(ws + 55050240);       // 9216
    bf16*  Qb    = (bf16*)(ws + 55059456);        // 50331648
    bf16*  Kb    = (bf16*)(ws + 105391104);       // 50331648
    bf16*  Vb    = (bf16*)(ws + 155722752);       // 50331648
    float* ssq   = (float*)(ws + 206054400);      // 24576
    float* ssk   = (float*)(ws + 206078976);      // 24576
    float* G     = (float*)(ws + 206103552);      // 1572864
    bf16*  attnT = (bf16*)(ws + 207676416);       // 786432
    bf16*  Yb    = xb;                            // alias: x no longer needed after QKV GEMM

    // zero atomic accumulators (ssq|ssk|G contiguous)
    hipMemsetAsync(ws + 206054400, 0, 24576 + 24576 + 1572864, stream);

    cast_x_kernel<<<12288, 256, 0, stream>>>(x, xb, BNTOK * EMB / 8);
    prep_w_kernel<<<9225, 256, 0, stream>>>(Wq, Wk, Wv, Wo, bq, bk, bv, WqkvT, WoT, bqkv);

    gemm_bt<0><<<dim3(18, 256), 256, 0, stream>>>(xb, WqkvT, BNTOK, 2304, 768,
                                                  Qb, Kb, Vb, bqkv, nullptr, nullptr);

    sumsq_kernel<<<dim3(16, 3, 8), 256, 0, stream>>>(Qb, Kb, ssq, ssk);
    gram_kernel<<<384, 256, 0, stream>>>(Qb, Kb, G);
    softmax_kernel<<<96, 64, 0, stream>>>(G, ssq, ssk, attnT);
    pv_kernel<<<dim3(16, NHEAD, BATCH), 256, 0, stream>>>(Vb, attnT, Yb);

    gemm_bt<1><<<dim3(6, 256), 256, 0, stream>>>(Yb, WoT, BNTOK, 768, 768,
                                                 nullptr, nullptr, nullptr, nullptr, out, bo);
}

// Round 2
// 377.047 us; speedup vs baseline: 1.0464x; 1.0464x over previous
//
#include <hip/hip_runtime.h>
#include <hip/hip_bf16.h>

// ---------- types ----------
typedef short bf16x8 __attribute__((ext_vector_type(8)));      // 8 bf16 in 4 VGPRs
typedef unsigned short u16x8 __attribute__((ext_vector_type(8)));
typedef float f32x4 __attribute__((ext_vector_type(4)));
using bf16 = __hip_bfloat16;

#define EMB 768
#define NHEAD 12
#define BATCH 8
#define NTOK 4096
#define BNTOK 32768   // BATCH*NTOK

__device__ __forceinline__ float b2f(unsigned short u) {
    union { unsigned int i; float f; } x; x.i = ((unsigned int)u) << 16; return x.f;
}
__device__ __forceinline__ unsigned short f2bu(float f) {
    bf16 h = __float2bfloat16(f);
    return *reinterpret_cast<unsigned short*>(&h);
}

__device__ __forceinline__ void gload_lds16(const void* g, void* l) {
    __builtin_amdgcn_global_load_lds(
        (const __attribute__((address_space(1))) unsigned int*)g,
        (__attribute__((address_space(3))) unsigned int*)l,
        16, 0, 0);
}

// ---------- cast x (fp32 -> bf16), vectorized ----------
__global__ __launch_bounds__(256) void cast_x_kernel(const float* __restrict__ x,
                                                     bf16* __restrict__ xb, int n8) {
    int i = blockIdx.x * blockDim.x + threadIdx.x;
    if (i >= n8) return;
    const float4* xv = (const float4*)x;
    float4 a = xv[i * 2], b = xv[i * 2 + 1];
    u16x8 o;
    o[0] = f2bu(a.x); o[1] = f2bu(a.y); o[2] = f2bu(a.z); o[3] = f2bu(a.w);
    o[4] = f2bu(b.x); o[5] = f2bu(b.y); o[6] = f2bu(b.z); o[7] = f2bu(b.w);
    ((u16x8*)xb)[i] = o;
}

// ---------- weight prep: W^T casts + stacked bias ----------
__global__ __launch_bounds__(256) void prep_w_kernel(
    const float* __restrict__ Wq, const float* __restrict__ Wk,
    const float* __restrict__ Wv, const float* __restrict__ Wo,
    const float* __restrict__ bq, const float* __restrict__ bk, const float* __restrict__ bv,
    bf16* __restrict__ WqkvT, bf16* __restrict__ WoT, float* __restrict__ bqkv) {
    const int NQKV = 2304 * 768, NO = 768 * 768;
    int i = blockIdx.x * blockDim.x + threadIdx.x;
    if (i < NQKV) {
        int nrow = i / 768, k = i % 768;
        const float* W = (nrow < 768) ? Wq : (nrow < 1536 ? Wk : Wv);
        int c = nrow % 768;
        WqkvT[i] = __float2bfloat16(W[k * 768 + c]);
    } else if (i < NQKV + NO) {
        int j = i - NQKV; int nrow = j / 768, k = j % 768;
        WoT[j] = __float2bfloat16(Wo[k * 768 + nrow]);
    } else if (i < NQKV + NO + 2304) {
        int j = i - NQKV - NO;
        bqkv[j] = (j < 768) ? bq[j] : (j < 1536 ? bk[j - 768] : bv[j - 1536]);
    }
}

// ---------- 256x256 8-wave counted-vmcnt bf16 GEMM, K=768, B^T input ----------
// LDS layout: [buf:2][A/B][Khalf:2] regions of 16KB. Within a region the
// logical (row 0..255, slot 0..3 of 16B) lives at physical byte
//   (row ^ ((row>>2)&1))*64 + ((slot ^ (row&3))<<4)
// staged via inverse-permuted global source (gload_lds dest linear).
// MODE 0: C -> Q/K/V bf16 (+bias). MODE 1: C fp32 -> Cout (+bo).
template <int MODE>
__global__ __launch_bounds__(512, 2) void gemm256(
    const bf16* __restrict__ A, const bf16* __restrict__ BT,
    bf16* __restrict__ Q, bf16* __restrict__ Kb, bf16* __restrict__ V,
    const float* __restrict__ bias,
    float* __restrict__ Cout, const float* __restrict__ bo) {
    __shared__ char lds[131072];
    const int NKT = 12;   // K = 768 = 12 * 64
    const int tid = threadIdx.x;
    const int lane = tid & 63, wid = tid >> 6;
    const int wm = wid >> 2, wn = wid & 3;          // 2 (M) x 4 (N) waves
    const int lrow = lane & 15, lk = lane >> 4;
    const int xsl = lrow & 3;
    const int lrsw = lrow ^ ((lrow >> 2) & 1);      // physical row offset for reads
    const int slotb = (lk ^ xsl) << 4;              // physical slot byte for reads

    // XCD-aware bijective swizzle (grid %8 == 0 for both uses)
    int nwg = gridDim.x * gridDim.y;
    int bid = blockIdx.y * gridDim.x + blockIdx.x;
    int swz = (bid & 7) * (nwg >> 3) + (bid >> 3);
    int bx = swz % gridDim.x, by = swz / gridDim.x;
    const int m0 = by * 256, n0 = bx * 256;

    // staging geometry: thread covers physical rows rstg and rstg+128
    const int rstg = tid >> 2;
    const int rl = rstg ^ ((rstg >> 2) & 1);                 // logical row for this phys row
    const int sl8 = (((tid & 3) ^ (rl & 3)) << 3);           // logical col offset (elems)

    f32x4 acc[8][4] = {};

#define STAGE(tbuf, isb, skh, sktv) do {                                          \
    int skt_ = (sktv); if (skt_ >= NKT) skt_ = NKT - 1;                           \
    const bf16* gp_ = ((isb) ? BT + (size_t)(n0 + rl) * 768                       \
                             : A  + (size_t)(m0 + rl) * 768)                      \
                      + skt_ * 64 + (skh) * 32 + sl8;                             \
    char* lp_ = lds + (tbuf) * 65536 + (isb) * 32768 + (skh) * 16384 + wid * 1024;\
    gload_lds16(gp_, lp_);                                                        \
    gload_lds16(gp_ + (size_t)128 * 768, lp_ + 8192);                             \
} while (0)

#define COMPUTE(cbuf, KH, CM) do {                                                \
    const char* ab_ = lds + (cbuf) * 65536 + (KH) * 16384;                        \
    const char* bb_ = ab_ + 32768;                                                \
    bf16x8 af_[4], bfv_[4];                                                       \
    _Pragma("unroll") for (int mi = 0; mi < 4; ++mi) {                            \
        int pr_ = wm * 128 + (CM) * 64 + mi * 16 + lrsw;                          \
        af_[mi] = *(const bf16x8*)(ab_ + pr_ * 64 + slotb); }                     \
    _Pragma("unroll") for (int ni = 0; ni < 4; ++ni) {                            \
        int pr_ = wn * 64 + ni * 16 + lrsw;                                       \
        bfv_[ni] = *(const bf16x8*)(bb_ + pr_ * 64 + slotb); }                    \
    __builtin_amdgcn_s_setprio(1);                                                \
    _Pragma("unroll") for (int mi = 0; mi < 4; ++mi)                              \
    _Pragma("unroll") for (int ni = 0; ni < 4; ++ni)                              \
        acc[(CM) * 4 + mi][ni] = __builtin_amdgcn_mfma_f32_16x16x32_bf16(         \
            af_[mi], bfv_[ni], acc[(CM) * 4 + mi][ni], 0, 0, 0);                  \
    __builtin_amdgcn_s_setprio(0);                                                \
} while (0)

#define VMC8 asm volatile("s_waitcnt vmcnt(8)" ::: "memory")
#define BAR  __builtin_amdgcn_s_barrier()

    // prologue: tile0 full + tile1 Kh0   (FIFO: Ah0(0) Bh0(0) Ah1(0) Bh1(0) Ah0(1) Bh0(1))
    STAGE(0, 0, 0, 0);
    STAGE(0, 1, 0, 0);
    STAGE(0, 0, 1, 0);
    STAGE(0, 1, 1, 0);
    STAGE(1, 0, 0, 1);
    STAGE(1, 1, 0, 1);
    VMC8; BAR;

    for (int i = 0; i < NKT; ++i) {
        const int cb = i & 1, nb = cb ^ 1;
        STAGE(nb, 0, 1, i + 1); COMPUTE(cb, 0, 0); BAR;
        STAGE(nb, 1, 1, i + 1); COMPUTE(cb, 0, 1); VMC8; BAR;
        STAGE(cb, 0, 0, i + 2); COMPUTE(cb, 1, 0); BAR;
        STAGE(cb, 1, 0, i + 2); COMPUTE(cb, 1, 1); VMC8; BAR;
    }

#undef STAGE
#undef COMPUTE
#undef VMC8
#undef BAR

    const int lq = lk;
    if (MODE == 0) {
        const int which = n0 / 768;   // 256-tile lies entirely in one of Q/K/V
        bf16* O = (which == 0) ? Q : (which == 1 ? Kb : V);
        const int cbase = n0 - which * 768 + wn * 64;
#pragma unroll
        for (int ri = 0; ri < 8; ++ri)
#pragma unroll
            for (int ni = 0; ni < 4; ++ni) {
                int gcol = n0 + wn * 64 + ni * 16 + lrow;
                float bia = bias[gcol];
                int col = cbase + ni * 16 + lrow;
                size_t r0 = (size_t)(m0 + wm * 128 + ri * 16 + lq * 4);
#pragma unroll
                for (int r = 0; r < 4; ++r)
                    O[(r0 + r) * 768 + col] = __float2bfloat16(acc[ri][ni][r] + bia);
            }
    } else {
#pragma unroll
        for (int ri = 0; ri < 8; ++ri)
#pragma unroll
            for (int ni = 0; ni < 4; ++ni) {
                int col = n0 + wn * 64 + ni * 16 + lrow;
                float bia = bo[col];
                size_t r0 = (size_t)(m0 + wm * 128 + ri * 16 + lq * 4);
#pragma unroll
                for (int r = 0; r < 4; ++r)
                    Cout[(r0 + r) * 768 + col] = acc[ri][ni][r] + bia;
            }
    }
}

// ---------- per-(b,channel) sum of squares over tokens ----------
__global__ __launch_bounds__(256) void sumsq_kernel(
    const bf16* __restrict__ Qb, const bf16* __restrict__ Kb,
    float* __restrict__ ssq, float* __restrict__ ssk) {
    int rc = blockIdx.x, ct = blockIdx.y, b = blockIdx.z;
    int col = ct * 256 + threadIdx.x;
    size_t base = ((size_t)b * NTOK + rc * 256) * 768 + col;
    float sq = 0.f, sk = 0.f;
    for (int i = 0; i < 256; ++i) {
        float q = b2f(*(const unsigned short*)&Qb[base + (size_t)i * 768]);
        float k = b2f(*(const unsigned short*)&Kb[base + (size_t)i * 768]);
        sq += q * q; sk += k * k;
    }
    atomicAdd(&ssq[b * 768 + col], sq);
    atomicAdd(&ssk[b * 768 + col], sk);
}

// ---------- Gram: G[bh][e][j] = sum_n Q[n][e] K[n][j] ----------
__global__ __launch_bounds__(256) void gram_kernel(
    const bf16* __restrict__ Qb, const bf16* __restrict__ Kb, float* __restrict__ G) {
    int bh = blockIdx.x >> 2, ch = blockIdx.x & 3;
    int b = bh / NHEAD, h = bh % NHEAD;
    const int t0 = ch * 1024;
    __shared__ float Qs[32][64];
    __shared__ float Ks[32][64];
    int tid = threadIdx.x;
    int e0 = (tid >> 4) << 2, j0 = (tid & 15) << 2;
    float acc[4][4] = {};
    const size_t base = ((size_t)b * NTOK) * 768 + h * 64;
    int lt = tid >> 3, lc = (tid & 7) << 3;
    for (int it = 0; it < 32; ++it) {
        int tok = t0 + it * 32;
        u16x8 qv = *(const u16x8*)(Qb + base + (size_t)(tok + lt) * 768 + lc);
        u16x8 kv = *(const u16x8*)(Kb + base + (size_t)(tok + lt) * 768 + lc);
        __syncthreads();
#pragma unroll
        for (int j = 0; j < 8; ++j) { Qs[lt][lc + j] = b2f(qv[j]); Ks[lt][lc + j] = b2f(kv[j]); }
        __syncthreads();
#pragma unroll
        for (int t = 0; t < 32; ++t) {
            float4 q4 = *(const float4*)&Qs[t][e0];
            float4 k4 = *(const float4*)&Ks[t][j0];
            float q[4] = {q4.x, q4.y, q4.z, q4.w};
            float k[4] = {k4.x, k4.y, k4.z, k4.w};
#pragma unroll
            for (int ii = 0; ii < 4; ++ii)
#pragma unroll
                for (int jj = 0; jj < 4; ++jj) acc[ii][jj] = fmaf(q[ii], k[jj], acc[ii][jj]);
        }
    }
#pragma unroll
    for (int ii = 0; ii < 4; ++ii)
#pragma unroll
        for (int jj = 0; jj < 4; ++jj)
            atomicAdd(&G[(size_t)bh * 4096 + (e0 + ii) * 64 + (j0 + jj)], acc[ii][jj]);
}

// ---------- normalize + softmax + /sqrt(E); store attn^T bf16 ----------
__global__ __launch_bounds__(64) void softmax_kernel(
    const float* __restrict__ G, const float* __restrict__ ssq, const float* __restrict__ ssk,
    bf16* __restrict__ attnT) {
    int bh = blockIdx.x; int b = bh / NHEAD, h = bh % NHEAD;
    int e = threadIdx.x;
    const float* g = G + (size_t)bh * 4096 + e * 64;
    float nq = fmaxf(sqrtf(ssq[b * 768 + h * 64 + e]), 1e-12f);
    float row[64];
    float mx = -1e30f;
#pragma unroll
    for (int j = 0; j < 64; ++j) {
        float nk = fmaxf(sqrtf(ssk[b * 768 + h * 64 + j]), 1e-12f);
        float en = g[j] / (nq * nk);
        row[j] = en;
        mx = fmaxf(mx, en);
    }
    float s = 0.f;
#pragma unroll
    for (int j = 0; j < 64; ++j) { row[j] = __expf(row[j] - mx); s += row[j]; }
    float inv = 0.036084391824351615f / s;   // (1/sqrt(768)) / sum
#pragma unroll
    for (int j = 0; j < 64; ++j)
        attnT[(size_t)bh * 4096 + j * 64 + e] = __float2bfloat16(row[j] * inv);
}

// ---------- PV: Y[b,n,h,:] = V[b,n,h,:] @ attn  (MFMA, K=64) ----------
__global__ __launch_bounds__(256) void pv_kernel(
    const bf16* __restrict__ V, const bf16* __restrict__ attnT, bf16* __restrict__ Y) {
    int tch = blockIdx.x;           // 16 chunks of 256 tokens
    int h = blockIdx.y, b = blockIdx.z;
    int bh = b * NHEAD + h;
    __shared__ bf16 Ats[64 * 64];
    int tid = threadIdx.x, lane = tid & 63, wid = tid >> 6;
    {
        const u16x8* src = (const u16x8*)(attnT + (size_t)bh * 4096);
        u16x8* dst = (u16x8*)Ats;
        dst[tid] = src[tid];
        dst[tid + 256] = src[tid + 256];
    }
    __syncthreads();
    f32x4 acc[4][4] = {};
    const int lrow = lane & 15, lk = lane >> 4;
    const int trow0 = tch * 256 + wid * 64;
#pragma unroll
    for (int ks = 0; ks < 2; ++ks) {
        bf16x8 a[4], bfr[4];
#pragma unroll
        for (int mi = 0; mi < 4; ++mi)
            a[mi] = *(const bf16x8*)(V + (size_t)(b * NTOK + trow0 + mi * 16 + lrow) * 768 +
                                     h * 64 + ks * 32 + lk * 8);
        const bf16x8* Bv = (const bf16x8*)Ats;
#pragma unroll
        for (int ni = 0; ni < 4; ++ni) bfr[ni] = Bv[(ni * 16 + lrow) * 8 + ks * 4 + lk];
#pragma unroll
        for (int mi = 0; mi < 4; ++mi)
#pragma unroll
            for (int ni = 0; ni < 4; ++ni)
                acc[mi][ni] = __builtin_amdgcn_mfma_f32_16x16x32_bf16(a[mi], bfr[ni], acc[mi][ni], 0, 0, 0);
    }
    const int lq = lane >> 4;
#pragma unroll
    for (int mi = 0; mi < 4; ++mi)
#pragma unroll
        for (int ni = 0; ni < 4; ++ni) {
            int col = ni * 16 + lrow;
#pragma unroll
            for (int r = 0; r < 4; ++r) {
                int row = trow0 + mi * 16 + lq * 4 + r;
                Y[(size_t)(b * NTOK + row) * 768 + h * 64 + col] = __float2bfloat16(acc[mi][ni][r]);
            }
        }
}

// ---------- launch ----------
extern "C" void kernel_launch(void* const* d_in, const int* in_sizes, int n_in,
                              void* d_out, int out_size, void* d_ws, size_t ws_size,
                              hipStream_t stream) {
    const float* x  = (const float*)d_in[0];
    const float* Wq = (const float*)d_in[1];
    const float* bq = (const float*)d_in[2];
    const float* Wk = (const float*)d_in[3];
    const float* bk = (const float*)d_in[4];
    const float* Wv = (const float*)d_in[5];
    const float* bv = (const float*)d_in[6];
    const float* Wo = (const float*)d_in[7];
    const float* bo = (const float*)d_in[8];
    float* out = (float*)d_out;

    char* ws = (char*)d_ws;
    bf16*  xb    = (bf16*)(ws + 0);               // 50331648 B ; reused as Y later
    bf16*  WqkvT = (bf16*)(ws + 50331648);        // 3538944
    bf16*  WoT   = (bf16*)(ws + 53870592);        // 1179648
    float* bqkv  = (float*)(ws + 55050240);       // 9216
    bf16*  Qb    = (bf16*)(ws + 55059456);        // 50331648
    bf16*  Kb    = (bf16*)(ws + 105391104);       // 50331648
    bf16*  Vb    = (bf16*)(ws + 155722752);       // 50331648
    float* ssq   = (float*)(ws + 206054400);      // 24576
    float* ssk   = (float*)(ws + 206078976);      // 24576
    float* G     = (float*)(ws + 206103552);      // 1572864
    bf16*  attnT = (bf16*)(ws + 207676416);       // 786432
    bf16*  Yb    = xb;                            // alias: x no longer needed after QKV GEMM

    // zero atomic accumulators (ssq|ssk|G contiguous)
    hipMemsetAsync(ws + 206054400, 0, 24576 + 24576 + 1572864, stream);

    cast_x_kernel<<<12288, 256, 0, stream>>>(x, xb, BNTOK * EMB / 8);
    prep_w_kernel<<<9225, 256, 0, stream>>>(Wq, Wk, Wv, Wo, bq, bk, bv, WqkvT, WoT, bqkv);

    gemm256<0><<<dim3(9, 128), 512, 0, stream>>>(xb, WqkvT, Qb, Kb, Vb, bqkv, nullptr, nullptr);

    sumsq_kernel<<<dim3(16, 3, 8), 256, 0, stream>>>(Qb, Kb, ssq, ssk);
    gram_kernel<<<384, 256, 0, stream>>>(Qb, Kb, G);
    softmax_kernel<<<96, 64, 0, stream>>>(G, ssq, ssk, attnT);
    pv_kernel<<<dim3(16, NHEAD, BATCH), 256, 0, stream>>>(Vb, attnT, Yb);

    gemm256<1><<<dim3(3, 128), 512, 0, stream>>>(Yb, WoT, nullptr, nullptr, nullptr, nullptr, out, bo);
}

// Round 4
// 357.187 us; speedup vs baseline: 1.1046x; 1.0556x over previous
//
#include <hip/hip_runtime.h>
#include <hip/hip_bf16.h>

// ---------- types ----------
typedef short bf16x8 __attribute__((ext_vector_type(8)));
typedef unsigned short u16x8 __attribute__((ext_vector_type(8)));
typedef unsigned short us4 __attribute__((ext_vector_type(4)));
typedef float f32x4 __attribute__((ext_vector_type(4)));
using bf16 = __hip_bfloat16;

#define EMB 768
#define NHEAD 12
#define BATCH 8
#define NTOK 4096
#define BNTOK 32768

__device__ __forceinline__ float b2f(unsigned short u) {
    union { unsigned int i; float f; } x; x.i = ((unsigned int)u) << 16; return x.f;
}
__device__ __forceinline__ unsigned short f2bu(float f) {
    bf16 h = __float2bfloat16(f);
    return *reinterpret_cast<unsigned short*>(&h);
}

__device__ __forceinline__ void gload_lds16(const void* g, void* l) {
    __builtin_amdgcn_global_load_lds(
        (const __attribute__((address_space(1))) unsigned int*)g,
        (__attribute__((address_space(3))) unsigned int*)l,
        16, 0, 0);
}

// ---------- cast x (fp32 -> bf16) ----------
__global__ __launch_bounds__(256) void cast_x_kernel(const float* __restrict__ x,
                                                     bf16* __restrict__ xb, int n8) {
    int i = blockIdx.x * blockDim.x + threadIdx.x;
    if (i >= n8) return;
    const float4* xv = (const float4*)x;
    float4 a = xv[i * 2], b = xv[i * 2 + 1];
    u16x8 o;
    o[0] = f2bu(a.x); o[1] = f2bu(a.y); o[2] = f2bu(a.z); o[3] = f2bu(a.w);
    o[4] = f2bu(b.x); o[5] = f2bu(b.y); o[6] = f2bu(b.z); o[7] = f2bu(b.w);
    ((u16x8*)xb)[i] = o;
}

// ---------- weight prep ----------
__global__ __launch_bounds__(256) void prep_w_kernel(
    const float* __restrict__ Wq, const float* __restrict__ Wk,
    const float* __restrict__ Wv, const float* __restrict__ Wo,
    const float* __restrict__ bq, const float* __restrict__ bk, const float* __restrict__ bv,
    bf16* __restrict__ WqkvT, bf16* __restrict__ WoT, float* __restrict__ bqkv) {
    const int NQKV = 2304 * 768, NO = 768 * 768;
    int i = blockIdx.x * blockDim.x + threadIdx.x;
    if (i < NQKV) {
        int nrow = i / 768, k = i % 768;
        const float* W = (nrow < 768) ? Wq : (nrow < 1536 ? Wk : Wv);
        int c = nrow % 768;
        WqkvT[i] = __float2bfloat16(W[k * 768 + c]);
    } else if (i < NQKV + NO) {
        int j = i - NQKV; int nrow = j / 768, k = j % 768;
        WoT[j] = __float2bfloat16(Wo[k * 768 + nrow]);
    } else if (i < NQKV + NO + 2304) {
        int j = i - NQKV - NO;
        bqkv[j] = (j < 768) ? bq[j] : (j < 1536 ? bk[j - 768] : bv[j - 1536]);
    }
}

// ---------- 256x256 8-wave counted-vmcnt bf16 GEMM, K=768, frag-major LDS ----------
// LDS region per (buf, op, khalf) = 16KB laid out as [msub:16][1KB frag of
// 16 lanes x 16B]. Fragment read = region + msub*1024 + lane*16 (conflict-free).
// Stage: phys = wid*1024 + lane*16 (+8192); global src row = g*128 + wid*16 +
// (lane&15), col8 = ((lane>>4)&3)*8 within the 32-elem K-half.
// MODE 0: A=xb, BT=WqkvT(2304x768): Q,K -> transposed [b][chan][tok]; V normal.
// MODE 1: A=V, BT=Wt per-batch (768x768): C fp32 + bo.
template <int MODE>
__global__ __launch_bounds__(512, 1) void gemm256(
    const bf16* __restrict__ A, const bf16* __restrict__ BT,
    bf16* __restrict__ QT, bf16* __restrict__ KT, bf16* __restrict__ V,
    const float* __restrict__ bias,
    float* __restrict__ Cout, const float* __restrict__ bo) {
    __shared__ char lds[131072];
    const int NKT = 12;
    const int tid = threadIdx.x;
    const int lane = tid & 63, wid = tid >> 6;
    const int wm = wid >> 2, wn = wid & 3;
    const int lrow = lane & 15, lk = lane >> 4;

    int nwg = gridDim.x * gridDim.y;
    int bid = blockIdx.y * gridDim.x + blockIdx.x;
    int swz = (bid & 7) * (nwg >> 3) + (bid >> 3);
    int bx = swz % gridDim.x, by = swz / gridDim.x;
    const int m0 = by * 256, n0 = bx * 256;

    const bf16* bt = BT + (MODE == 1 ? (size_t)(m0 >> 12) * 589824 : 0);

    // staging source geometry
    const int srow = wid * 16 + lrow;          // rows srow, srow+128
    const int scol = ((lane >> 4) & 3) << 3;   // 8-elem offset in K-half

    f32x4 acc[8][4] = {};

#define STAGE(tbuf, isb, skh, sktv) do {                                           \
    int skt_ = (sktv); if (skt_ >= NKT) skt_ = NKT - 1;                            \
    const bf16* gp_ = ((isb) ? bt + (size_t)(n0 + srow) * 768                      \
                             : A  + (size_t)(m0 + srow) * 768)                     \
                      + skt_ * 64 + (skh) * 32 + scol;                             \
    char* lp_ = lds + (tbuf) * 65536 + (isb) * 32768 + (skh) * 16384 + wid * 1024; \
    gload_lds16(gp_, lp_);                                                         \
    gload_lds16(gp_ + (size_t)128 * 768, lp_ + 8192);                              \
} while (0)

#define LOADB(cbuf, KH) do {                                                       \
    const char* bb_ = lds + (cbuf) * 65536 + 32768 + (KH) * 16384;                 \
    _Pragma("unroll") for (int ni = 0; ni < 4; ++ni)                               \
        bre[ni] = *(const bf16x8*)(bb_ + (wn * 4 + ni) * 1024 + lane * 16);        \
} while (0)

#define COMPUTE(cbuf, KH, CM) do {                                                 \
    const char* ab_ = lds + (cbuf) * 65536 + (KH) * 16384;                         \
    bf16x8 af_[4];                                                                 \
    _Pragma("unroll") for (int mi = 0; mi < 4; ++mi)                               \
        af_[mi] = *(const bf16x8*)(ab_ + (wm * 8 + (CM) * 4 + mi) * 1024 + lane * 16); \
    __builtin_amdgcn_s_setprio(1);                                                 \
    _Pragma("unroll") for (int mi = 0; mi < 4; ++mi)                               \
    _Pragma("unroll") for (int ni = 0; ni < 4; ++ni)                               \
        acc[(CM) * 4 + mi][ni] = __builtin_amdgcn_mfma_f32_16x16x32_bf16(          \
            af_[mi], bre[ni], acc[(CM) * 4 + mi][ni], 0, 0, 0);                    \
    __builtin_amdgcn_s_setprio(0);                                                 \
} while (0)

#define VMC8 asm volatile("s_waitcnt vmcnt(8)" ::: "memory")
#define BAR  __builtin_amdgcn_s_barrier()

    bf16x8 bre[4];

    STAGE(0, 0, 0, 0);
    STAGE(0, 1, 0, 0);
    STAGE(0, 0, 1, 0);
    STAGE(0, 1, 1, 0);
    STAGE(1, 0, 0, 1);
    STAGE(1, 1, 0, 1);
    VMC8; BAR;

    for (int i = 0; i < NKT; ++i) {
        const int cb = i & 1, nb = cb ^ 1;
        STAGE(nb, 0, 1, i + 1); LOADB(cb, 0); COMPUTE(cb, 0, 0); BAR;
        STAGE(nb, 1, 1, i + 1); COMPUTE(cb, 0, 1); VMC8; BAR;
        STAGE(cb, 0, 0, i + 2); LOADB(cb, 1); COMPUTE(cb, 1, 0); BAR;
        STAGE(cb, 1, 0, i + 2); COMPUTE(cb, 1, 1); VMC8; BAR;
    }

#undef STAGE
#undef LOADB
#undef COMPUTE
#undef VMC8
#undef BAR

    if (MODE == 0) {
        const int which = n0 / 768;
        if (which < 2) {
            bf16* T = (which == 0) ? QT : KT;
            const int b = m0 >> 12;
            const int tb = (m0 & 4095) + wm * 128 + lk * 4;
#pragma unroll
            for (int ri = 0; ri < 8; ++ri)
#pragma unroll
                for (int ni = 0; ni < 4; ++ni) {
                    int gcol = n0 + wn * 64 + ni * 16 + lrow;
                    int chan = gcol - which * 768;
                    float bia = bias[gcol];
                    int tokl = tb + ri * 16;
                    us4 pk;
                    pk[0] = f2bu(acc[ri][ni][0] + bia);
                    pk[1] = f2bu(acc[ri][ni][1] + bia);
                    pk[2] = f2bu(acc[ri][ni][2] + bia);
                    pk[3] = f2bu(acc[ri][ni][3] + bia);
                    *(us4*)&T[((size_t)b * 768 + chan) * 4096 + tokl] = pk;
                }
        } else {
#pragma unroll
            for (int ri = 0; ri < 8; ++ri)
#pragma unroll
                for (int ni = 0; ni < 4; ++ni) {
                    int gcol = n0 + wn * 64 + ni * 16 + lrow;
                    int chan = gcol - 1536;
                    float bia = bias[gcol];
                    size_t r0 = (size_t)(m0 + wm * 128 + ri * 16 + lk * 4);
#pragma unroll
                    for (int r = 0; r < 4; ++r)
                        V[(r0 + r) * 768 + chan] = __float2bfloat16(acc[ri][ni][r] + bia);
                }
        }
    } else {
#pragma unroll
        for (int ri = 0; ri < 8; ++ri)
#pragma unroll
            for (int ni = 0; ni < 4; ++ni) {
                int col = n0 + wn * 64 + ni * 16 + lrow;
                float bia = bo[col];
                size_t r0 = (size_t)(m0 + wm * 128 + ri * 16 + lk * 4);
#pragma unroll
                for (int r = 0; r < 4; ++r)
                    Cout[(r0 + r) * 768 + col] = acc[ri][ni][r] + bia;
            }
    }
}

// ---------- Gram via MFMA over tokens + fused ssq/ssk ----------
// QT,KT: [b][768][4096] bf16. Block (kc, bh): 4 waves, wave w covers tokens
// kc*512 + w*128 .. +127.  G[bh][e][j] += sum_n QT[e][n] KT[j][n].
__global__ __launch_bounds__(256) void gram_mfma_kernel(
    const bf16* __restrict__ QT, const bf16* __restrict__ KT,
    float* __restrict__ G, float* __restrict__ ssq, float* __restrict__ ssk) {
    const int kc = blockIdx.x, bh = blockIdx.y;
    const int b = bh / NHEAD, h = bh % NHEAD;
    const int tid = threadIdx.x, lane = tid & 63, w = tid >> 6;
    const int lrow = lane & 15, lk = lane >> 4;
    const int t0 = kc * 512 + w * 128;

    f32x4 acc[4][4] = {};
    float sqp[4] = {}, skp[4] = {};
    const size_t qbase = ((size_t)b * 768 + h * 64) * 4096;

#pragma unroll
    for (int kk = 0; kk < 4; ++kk) {
        bf16x8 a[4], bb[4];
#pragma unroll
        for (int mi = 0; mi < 4; ++mi)
            a[mi] = *(const bf16x8*)(QT + qbase + (size_t)(mi * 16 + lrow) * 4096 +
                                     t0 + kk * 32 + lk * 8);
#pragma unroll
        for (int ni = 0; ni < 4; ++ni)
            bb[ni] = *(const bf16x8*)(KT + qbase + (size_t)(ni * 16 + lrow) * 4096 +
                                      t0 + kk * 32 + lk * 8);
#pragma unroll
        for (int mi = 0; mi < 4; ++mi) {
#pragma unroll
            for (int j = 0; j < 8; ++j) {
                float qv = b2f((unsigned short)a[mi][j]);
                float kv = b2f((unsigned short)bb[mi][j]);
                sqp[mi] = fmaf(qv, qv, sqp[mi]);
                skp[mi] = fmaf(kv, kv, skp[mi]);
            }
        }
#pragma unroll
        for (int mi = 0; mi < 4; ++mi)
#pragma unroll
            for (int ni = 0; ni < 4; ++ni)
                acc[mi][ni] = __builtin_amdgcn_mfma_f32_16x16x32_bf16(a[mi], bb[ni], acc[mi][ni], 0, 0, 0);
    }

    // ssq/ssk: reduce over lk groups (lanes l, l+16, l+32, l+48)
#pragma unroll
    for (int mi = 0; mi < 4; ++mi) {
        float vq = sqp[mi], vk = skp[mi];
        vq += __shfl_down(vq, 32); vq += __shfl_down(vq, 16);
        vk += __shfl_down(vk, 32); vk += __shfl_down(vk, 16);
        if (lane < 16) {
            atomicAdd(&ssq[b * 768 + h * 64 + mi * 16 + lrow], vq);
            atomicAdd(&ssk[b * 768 + h * 64 + mi * 16 + lrow], vk);
        }
    }

    float* g = G + (size_t)bh * 4096;
#pragma unroll
    for (int mi = 0; mi < 4; ++mi)
#pragma unroll
        for (int ni = 0; ni < 4; ++ni)
#pragma unroll
            for (int r = 0; r < 4; ++r) {
                int e = mi * 16 + lk * 4 + r;
                int j = ni * 16 + lrow;
                atomicAdd(&g[e * 64 + j], acc[mi][ni][r]);
            }
}

// ---------- normalize + softmax + /sqrt(E); store attnA[e][q] bf16 ----------
__global__ __launch_bounds__(64) void softmax_kernel(
    const float* __restrict__ G, const float* __restrict__ ssq, const float* __restrict__ ssk,
    bf16* __restrict__ attnA) {
    int bh = blockIdx.x; int b = bh / NHEAD, h = bh % NHEAD;
    int e = threadIdx.x;
    const float* g = G + (size_t)bh * 4096 + e * 64;
    float nq = fmaxf(sqrtf(ssq[b * 768 + h * 64 + e]), 1e-12f);
    float row[64];
    float mx = -1e30f;
#pragma unroll
    for (int j = 0; j < 64; ++j) {
        float nk = fmaxf(sqrtf(ssk[b * 768 + h * 64 + j]), 1e-12f);
        float en = g[j] / (nq * nk);
        row[j] = en;
        mx = fmaxf(mx, en);
    }
    float s = 0.f;
#pragma unroll
    for (int j = 0; j < 64; ++j) { row[j] = __expf(row[j] - mx); s += row[j]; }
    float inv = 0.036084391824351615f / s;
#pragma unroll
    for (int j = 0; j < 64; ++j)
        attnA[(size_t)bh * 4096 + e * 64 + j] = __float2bfloat16(row[j] * inv);
}

// ---------- Wtilde: WtT[b][n][h*64+e] = sum_q attn[b,e,h,q] Wo[h*64+q][n] ----------
// MFMA: A[m=n, k=q] = WoT[n][h*64+q]; B[k=q, col=e] = attnA[bh][e][q]. K=64.
__global__ __launch_bounds__(256) void wtilde_kernel(
    const bf16* __restrict__ WoT, const bf16* __restrict__ attnA,
    bf16* __restrict__ WtT) {
    const int ns = blockIdx.x, bh = blockIdx.y;
    const int b = bh / NHEAD, h = bh % NHEAD;
    const int tid = threadIdx.x, lane = tid & 63, w = tid >> 6;
    const int lrow = lane & 15, lk = lane >> 4;
    const int nbase = ns * 192 + w * 48;

    f32x4 acc[3][4] = {};
#pragma unroll
    for (int kk = 0; kk < 2; ++kk) {
        bf16x8 a[3], bb[4];
#pragma unroll
        for (int mi = 0; mi < 3; ++mi)
            a[mi] = *(const bf16x8*)(WoT + (size_t)(nbase + mi * 16 + lrow) * 768 +
                                     h * 64 + kk * 32 + lk * 8);
#pragma unroll
        for (int ni = 0; ni < 4; ++ni)
            bb[ni] = *(const bf16x8*)(attnA + (size_t)bh * 4096 +
                                      (ni * 16 + lrow) * 64 + kk * 32 + lk * 8);
#pragma unroll
        for (int mi = 0; mi < 3; ++mi)
#pragma unroll
            for (int ni = 0; ni < 4; ++ni)
                acc[mi][ni] = __builtin_amdgcn_mfma_f32_16x16x32_bf16(a[mi], bb[ni], acc[mi][ni], 0, 0, 0);
    }
#pragma unroll
    for (int mi = 0; mi < 3; ++mi)
#pragma unroll
        for (int ni = 0; ni < 4; ++ni)
#pragma unroll
            for (int r = 0; r < 4; ++r) {
                int n = nbase + mi * 16 + lk * 4 + r;
                int e = ni * 16 + lrow;
                WtT[((size_t)b * 768 + n) * 768 + h * 64 + e] = __float2bfloat16(acc[mi][ni][r]);
            }
}

// ---------- launch ----------
extern "C" void kernel_launch(void* const* d_in, const int* in_sizes, int n_in,
                              void* d_out, int out_size, void* d_ws, size_t ws_size,
                              hipStream_t stream) {
    const float* x  = (const float*)d_in[0];
    const float* Wq = (const float*)d_in[1];
    const float* bq = (const float*)d_in[2];
    const float* Wk = (const float*)d_in[3];
    const float* bk = (const float*)d_in[4];
    const float* Wv = (const float*)d_in[5];
    const float* bv = (const float*)d_in[6];
    const float* Wo = (const float*)d_in[7];
    const float* bo = (const float*)d_in[8];
    float* out = (float*)d_out;

    char* ws = (char*)d_ws;
    bf16*  xb    = (bf16*)(ws + 0);               // 50331648 ; later reused for WtT
    bf16*  WqkvT = (bf16*)(ws + 50331648);        // 3538944
    bf16*  WoT   = (bf16*)(ws + 53870592);        // 1179648
    float* bqkv  = (float*)(ws + 55050240);       // 9216
    bf16*  QT    = (bf16*)(ws + 55059456);        // 50331648  [b][768][4096]
    bf16*  KT    = (bf16*)(ws + 105391104);       // 50331648  [b][768][4096]
    bf16*  Vb    = (bf16*)(ws + 155722752);       // 50331648  [bn][768]
    float* ssq   = (float*)(ws + 206054400);      // 24576
    float* ssk   = (float*)(ws + 206078976);      // 24576
    float* G     = (float*)(ws + 206103552);      // 1572864
    bf16*  attnA = (bf16*)(ws + 207676416);       // 786432
    bf16*  WtT   = xb;                            // alias: xb dead after QKV GEMM

    hipMemsetAsync(ws + 206054400, 0, 24576 + 24576 + 1572864, stream);

    cast_x_kernel<<<12288, 256, 0, stream>>>(x, xb, BNTOK * EMB / 8);
    prep_w_kernel<<<9225, 256, 0, stream>>>(Wq, Wk, Wv, Wo, bq, bk, bv, WqkvT, WoT, bqkv);

    gemm256<0><<<dim3(9, 128), 512, 0, stream>>>(xb, WqkvT, QT, KT, Vb, bqkv, nullptr, nullptr);

    gram_mfma_kernel<<<dim3(8, 96), 256, 0, stream>>>(QT, KT, G, ssq, ssk);
    softmax_kernel<<<96, 64, 0, stream>>>(G, ssq, ssk, attnA);
    wtilde_kernel<<<dim3(4, 96), 256, 0, stream>>>(WoT, attnA, WtT);

    gemm256<1><<<dim3(3, 128), 512, 0, stream>>>(Vb, WtT, nullptr, nullptr, nullptr, nullptr, out, bo);
}